// Round 18
// baseline (137.353 us; speedup 1.0000x reference)
//
#include <hip/hip_runtime.h>
#include <math.h>

namespace {

constexpr int Bb = 16;
constexpr int Ll = 1024;
constexpr int Dd = 512;
constexpr int TOPK = 6;
constexpr int Kc = 512;

typedef short  short4v __attribute__((ext_vector_type(4)));
typedef short  short8 __attribute__((ext_vector_type(8)));
typedef float  f32x4  __attribute__((ext_vector_type(4)));

__device__ __forceinline__ short f2bf(float x) {
  unsigned u = __builtin_bit_cast(unsigned, x);
  u += 0x7fffu + ((u >> 16) & 1u);          // RNE
  return (short)(u >> 16);
}
__device__ __forceinline__ float bf2f(short b) {
  unsigned u = ((unsigned)(unsigned short)b) << 16;
  return __builtin_bit_cast(float, u);
}
__device__ __forceinline__ void g2l16(const void* g, void* l) {
  __builtin_amdgcn_global_load_lds(
      (const __attribute__((address_space(1))) unsigned*)g,
      (__attribute__((address_space(3))) unsigned*)l, 16, 0, 0);
}
__device__ __forceinline__ short8 cvt8(float4 a, float4 b) {
  short8 o;
  o[0] = f2bf(a.x); o[1] = f2bf(a.y); o[2] = f2bf(a.z); o[3] = f2bf(a.w);
  o[4] = f2bf(b.x); o[5] = f2bf(b.y); o[6] = f2bf(b.z); o[7] = f2bf(b.w);
  return o;
}
__device__ __forceinline__ int rev10(int k) {
  return (int)(__builtin_bitreverse32((unsigned)k) >> 22);
}
__device__ __forceinline__ float2 cmul(float2 z, float2 w) {
  return make_float2(z.x * w.x - z.y * w.y, z.x * w.y + z.y * w.x);
}

#define BARRIER() do { asm volatile("" ::: "memory"); \
    __builtin_amdgcn_s_barrier(); \
    asm volatile("" ::: "memory"); } while (0)
#define VMCNT8() asm volatile("s_waitcnt vmcnt(8)" ::: "memory")
#define VMCNT4() asm volatile("s_waitcnt vmcnt(4)" ::: "memory")
#define VMCNT0() asm volatile("s_waitcnt vmcnt(0)" ::: "memory")
#define LGKM0()  do { asm volatile("s_waitcnt lgkmcnt(0)" ::: "memory"); \
    __builtin_amdgcn_sched_barrier(0); } while (0)

// ===========================================================================
// r10's g64 (refcheck'd): NT GEMM, 128x128 tile, BK=64 (8 K-steps), 256 thr
// (4 waves, 2m x 2n of 64x64), depth-2 LDS ring, counted entry-vmcnt,
// XOR-swizzled LDS.
// MODE 0: tiny — blocks 0..31: Gt/Ht GEMM (A,B bf16 -> C bf16).
//         blocks 32..543: K fp32 [b][t][he] -> kbT bf16 [b][he][t]
//         (32x32 LDS tile transpose, 16 tiles/block).
// MODE 1: front — A fp32 (split-stage + cvt), B bf16.
//         z==0: T = Q@Gt^T stored TRANSPOSED as Tt[b][he][t] (bf16).
//         z==1: U = V@Ht^T stored row-major [b][t][he] (bf16).
// ===========================================================================
template<int MODE>
__global__ __launch_bounds__(256) void g64(
    const void* __restrict__ A0, const void* __restrict__ A1,
    const short* __restrict__ B0, const short* __restrict__ B1,
    void* __restrict__ C0, void* __restrict__ C1,
    const float* __restrict__ KfIn, short* __restrict__ kbOut)
{
  __shared__ short lds[2][16384];   // per buf: A [0,8192), B [8192,16384)

  const int tid = threadIdx.x;
  int z, m0, n0;
  if (MODE == 0) {
    if (blockIdx.x >= 32) {                    // K -> kbT transpose slice
      float (*tf)[33] = (float(*)[33])lds;
      const int ci = blockIdx.x - 32;          // 0..511
      const int r8 = tid >> 5, cc = tid & 31;
      const int her = tid >> 3, c4 = (tid & 7) * 4;
#pragma unroll 1
      for (int it = 0; it < 16; ++it) {
        const int tile = ci * 16 + it;         // 8192 tiles: b(16) x ti(32) x hh(16)
        const int b  = tile >> 9;
        const int ti = (tile >> 4) & 31;
        const int hh = tile & 15;
        const float* src = KfIn + ((size_t)b * 1024 + ti * 32) * 512 + hh * 32;
#pragma unroll
        for (int rr = 0; rr < 4; ++rr)
          tf[r8 + rr * 8][cc] = src[(size_t)(r8 + rr * 8) * 512 + cc];
        __syncthreads();
        short4v o;
#pragma unroll
        for (int e = 0; e < 4; ++e) o[e] = f2bf(tf[c4 + e][her]);
        *(short4v*)&kbOut[((size_t)b * 512 + hh * 32 + her) * 1024 + ti * 32 + c4] = o;
        __syncthreads();
      }
      return;
    }
    z = blockIdx.x >> 4;
    const int s = blockIdx.x & 15;
    m0 = (s >> 2) * 128;  n0 = (s & 3) * 128;
  } else {
    z = blockIdx.z;
    const int fb = blockIdx.x;                 // 512, XCD chunk = 64
    const int s  = (fb & 7) * 64 + (fb >> 3);
    m0 = (s >> 2) * 128;  n0 = (s & 3) * 128;
  }

  const int rS  = tid >> 3;                    // 0..31
  const int c8S = (tid & 7) ^ (rS & 7);        // swizzled source 16B-slot
  const short* Ga = nullptr;  const float* Fa = nullptr;
  const short* Gb = nullptr;
  if (MODE == 0) {
    Ga = (const short*)(z ? A1 : A0) + (size_t)(m0 + rS) * Kc + c8S * 8;
    Gb = (z ? B1 : B0) + (size_t)(n0 + rS) * Kc + c8S * 8;
  } else {
    Fa = (const float*)(z ? A1 : A0) + (size_t)(m0 + rS) * Kc + c8S * 8;
    Gb = (z ? B1 : B0) + (size_t)(n0 + rS) * Kc + c8S * 8;
  }

  const int lane = tid & 63;
  const int wid  = tid >> 6;
  const int wr = wid >> 1, wn = wid & 1;
  const int lo = lane & 15, hi = lane >> 4;
  int aoff[2][4], boff[2][4];
#pragma unroll
  for (int i = 0; i < 4; ++i) {
    const int ar = wr * 64 + i * 16 + lo;
    const int br = wn * 64 + i * 16 + lo;
#pragma unroll
    for (int ks = 0; ks < 2; ++ks) {
      aoff[ks][i] = (ar * 8 + ((ks * 4 + hi) ^ (ar & 7))) * 8;
      boff[ks][i] = 8192 + (br * 8 + ((ks * 4 + hi) ^ (br & 7))) * 8;
    }
  }

  f32x4 acc[4][4];
#pragma unroll
  for (int i = 0; i < 4; ++i)
#pragma unroll
    for (int j = 0; j < 4; ++j) acc[i][j] = (f32x4){0.f, 0.f, 0.f, 0.f};

#define SG_A(buf, kt) do { _Pragma("unroll") \
    for (int i_ = 0; i_ < 4; ++i_) \
      g2l16(Ga + (size_t)i_ * 32 * Kc + (kt) * 64, &lds[buf][(i_ * 256 + tid) * 8]); } while (0)
#define SG_B(buf, kt) do { _Pragma("unroll") \
    for (int i_ = 0; i_ < 4; ++i_) \
      g2l16(Gb + (size_t)i_ * 32 * Kc + (kt) * 64, &lds[buf][8192 + (i_ * 256 + tid) * 8]); } while (0)
#define LD_F(eV, F, kt) do { _Pragma("unroll") \
    for (int i_ = 0; i_ < 4; ++i_) { \
      eV[2 * i_]     = *(const float4*)((F) + (size_t)i_ * 32 * Kc + (kt) * 64); \
      eV[2 * i_ + 1] = *(const float4*)((F) + (size_t)i_ * 32 * Kc + (kt) * 64 + 4); } } while (0)
#define WR_F(buf, opb, eV) do { _Pragma("unroll") \
    for (int i_ = 0; i_ < 4; ++i_) \
      *(short8*)&lds[buf][(opb) + (i_ * 256 + tid) * 8] = cvt8(eV[2 * i_], eV[2 * i_ + 1]); } while (0)

  {
    float4 e[8];
    if (MODE == 1) {
      SG_B(0, 0); LD_F(e, Fa, 0); WR_F(0, 0, e);
      SG_B(1, 1); LD_F(e, Fa, 1); WR_F(1, 0, e);
    } else {
      SG_A(0, 0); SG_B(0, 0);
      SG_A(1, 1); SG_B(1, 1);
    }
  }

  int cur = 0;
#pragma unroll 1
  for (int t = 0; t < 8; ++t) {
    if (t == 7)            VMCNT0();
    else if (MODE == 0)    VMCNT8();
    else                   VMCNT4();
    LGKM0();
    BARRIER();

    const short* L = lds[cur];
    const bool pf = (t < 6);
    float4 e[8];

    short8 af[4], bq[4];
#pragma unroll
    for (int i = 0; i < 4; ++i) af[i] = *(const short8*)(L + aoff[0][i]);
#pragma unroll
    for (int j = 0; j < 4; ++j) bq[j] = *(const short8*)(L + boff[0][j]);
    if (pf && MODE == 1) LD_F(e, Fa, t + 2);
#pragma unroll
    for (int i = 0; i < 4; ++i)
#pragma unroll
      for (int j = 0; j < 4; ++j)
        acc[i][j] = __builtin_amdgcn_mfma_f32_16x16x32_bf16(af[i], bq[j], acc[i][j], 0, 0, 0);
#pragma unroll
    for (int i = 0; i < 4; ++i) af[i] = *(const short8*)(L + aoff[1][i]);
#pragma unroll
    for (int j = 0; j < 4; ++j) bq[j] = *(const short8*)(L + boff[1][j]);
#pragma unroll
    for (int i = 0; i < 4; ++i)
#pragma unroll
      for (int j = 0; j < 4; ++j)
        acc[i][j] = __builtin_amdgcn_mfma_f32_16x16x32_bf16(af[i], bq[j], acc[i][j], 0, 0, 0);

    BARRIER();

    if (pf) {
      if (MODE == 1)      { SG_B(cur, t + 2); WR_F(cur, 0, e); }
      else                { SG_A(cur, t + 2); SG_B(cur, t + 2); }
    }
    cur ^= 1;
  }
#undef SG_A
#undef SG_B
#undef LD_F
#undef WR_F

  if (MODE == 1 && z == 0) {
    // transposed store: Tt[b][he][t], 4 consecutive t per short4
    short* Tt = (short*)C0;
#pragma unroll
    for (int i = 0; i < 4; ++i) {
      const int rowb = m0 + wr * 64 + i * 16 + hi * 4;       // global t-row, 4-aligned
      const size_t bbase = (size_t)(rowb >> 10) * 512;       // batch * 512 he
#pragma unroll
      for (int j = 0; j < 4; ++j) {
        const int col = n0 + wn * 64 + j * 16 + lo;          // he
        short4v o;
#pragma unroll
        for (int r = 0; r < 4; ++r) o[r] = f2bf(acc[i][j][r]);
        *(short4v*)&Tt[(bbase + col) * 1024 + (rowb & 1023)] = o;
      }
    }
  } else {
    short* C = (short*)(z ? C1 : C0);
#pragma unroll
    for (int i = 0; i < 4; ++i)
#pragma unroll
      for (int r = 0; r < 4; ++r) {
        const size_t row = m0 + wr * 64 + i * 16 + hi * 4 + r;
#pragma unroll
        for (int j = 0; j < 4; ++j)
          C[row * Dd + n0 + wn * 64 + j * 16 + lo] = f2bf(acc[i][j][r]);
      }
  }
}

// ===========================================================================
// fftcorr v3: RADIX-4 (5 stages vs 10 -> half the barriers, half the LDS
// traffic, half the conflicts).  Same extraction as r15/r16 (validated):
// bit-reversed output order preserved via the bitrev2 slot trick
// (y_j stored at slot {0,2,1,3}[j]; verified exactly at N=4).
// 1024 blocks = 16 b x 64 he-groups (8 he each), XI index skew kept.
// Twiddle: y_j *= W1024^(pos*j*4^s)  (full 1024-entry table, e3 <= 765).
// ===========================================================================
#define XI(i) ((i) + ((i) >> 4))
__global__ __launch_bounds__(256) void fftcorr(
    const short* __restrict__ Tt, const short* __restrict__ kbT,
    float* __restrict__ Sg)
{
  __shared__ float2 x[1088];                   // 1024 + 64 pad (XI skew)
  __shared__ float2 tw[1024];
  __shared__ float2 sac[513];

  const int tid = threadIdx.x;
  const int b   = blockIdx.x >> 6;
  const int he0 = (blockIdx.x & 63) * 8;

  for (int j = tid; j < 1024; j += 256) {
    float sv, cv;
    sincosf(6.283185307179586f * (float)j / 1024.f, &sv, &cv);
    tw[j] = make_float2(cv, -sv);              // W = exp(-2*pi*i*j/1024)
  }
  for (int k = tid; k < 513; k += 256) sac[k] = make_float2(0.f, 0.f);
  __syncthreads();

#pragma unroll 1
  for (int he = 0; he < 8; ++he) {
    const short* q = Tt  + ((size_t)b * 512 + he0 + he) * 1024;
    const short* p = kbT + ((size_t)b * 512 + he0 + he) * 1024;
    {
      const int t4 = tid * 4;
      const short4v qv = *(const short4v*)&q[t4];
      const short4v pv = *(const short4v*)&p[t4];
#pragma unroll
      for (int e = 0; e < 4; ++e)
        x[XI(t4 + e)] = make_float2(bf2f(qv[e]), bf2f(pv[e]));
    }
    __syncthreads();

    // 5 radix-4 DIF stages: h = 256, 64, 16, 4, 1
#pragma unroll
    for (int s = 0; s < 5; ++s) {
      const int l2h = 8 - 2 * s;
      const int h   = 1 << l2h;
      const int pos = tid & (h - 1);
      const int i0  = ((tid >> l2h) << (l2h + 2)) + pos;
      const float2 a = x[XI(i0)];
      const float2 bv = x[XI(i0 + h)];
      const float2 c = x[XI(i0 + 2 * h)];
      const float2 d = x[XI(i0 + 3 * h)];
      const float2 apc = make_float2(a.x + c.x, a.y + c.y);
      const float2 amc = make_float2(a.x - c.x, a.y - c.y);
      const float2 bpd = make_float2(bv.x + d.x, bv.y + d.y);
      const float2 bmd = make_float2(bv.x - d.x, bv.y - d.y);
      const float2 y0 = make_float2(apc.x + bpd.x, apc.y + bpd.y);
      const float2 y2 = make_float2(apc.x - bpd.x, apc.y - bpd.y);
      const float2 y1 = make_float2(amc.x + bmd.y, amc.y - bmd.x);   // amc - i*bmd
      const float2 y3 = make_float2(amc.x - bmd.y, amc.y + bmd.x);   // amc + i*bmd
      const int e1 = pos << (2 * s);
      x[XI(i0)]         = y0;
      x[XI(i0 + h)]     = cmul(y2, tw[2 * e1]);   // slot1 <- j=2
      x[XI(i0 + 2 * h)] = cmul(y1, tw[e1]);       // slot2 <- j=1
      x[XI(i0 + 3 * h)] = cmul(y3, tw[3 * e1]);
      __syncthreads();
    }

    // extraction: A = (Z[k]+conj(Z[N-k]))/2, B = (Z[k]-conj(Z[N-k]))/(2i),
    // S += A*conj(B)
#pragma unroll
    for (int kk = 0; kk < 3; ++kk) {
      const int k = (kk < 2) ? (tid + kk * 256) : 512;
      if (kk < 2 || tid == 0) {
        const float2 Zk = x[XI(rev10(k))];
        const float2 Zm = x[XI(rev10((1024 - k) & 1023))];
        const float2 A = make_float2(0.5f * (Zk.x + Zm.x), 0.5f * (Zk.y - Zm.y));
        const float2 B = make_float2(0.5f * (Zk.y + Zm.y), -0.5f * (Zk.x - Zm.x));
        sac[k].x += A.x * B.x + A.y * B.y;
        sac[k].y += A.y * B.x - A.x * B.y;
      }
    }
    __syncthreads();
  }

  for (int k = tid; k < 513; k += 256) {
    atomicAdd(&Sg[((size_t)b * 513 + k) * 2 + 0], sac[k].x);
    atomicAdd(&Sg[((size_t)b * 513 + k) * 2 + 1], sac[k].y);
  }
}

// ===========================================================================
// ifft_mv: mv[b][l] = irfft(Sg[b])[l].  Hermitian extension to 1024, one
// conj-twiddle radix-2 DIF FFT, output (bit-reversed) real part / 1024.
// ===========================================================================
__global__ __launch_bounds__(256) void ifft_mv(
    const float* __restrict__ Sg, float* __restrict__ mv)
{
  __shared__ float2 x[1088];
  __shared__ float2 tw[512];
  const int tid = threadIdx.x;
  const int b = blockIdx.x;

  for (int j = tid; j < 512; j += 256) {
    float sv, cv;
    sincosf(6.283185307179586f * (float)j / 1024.f, &sv, &cv);
    tw[j] = make_float2(cv, sv);               // conjugate twiddles
  }
  for (int k = tid; k < 1024; k += 256) {
    if (k <= 512)
      x[XI(k)] = make_float2(Sg[((size_t)b * 513 + k) * 2], Sg[((size_t)b * 513 + k) * 2 + 1]);
    else
      x[XI(k)] = make_float2(Sg[((size_t)b * 513 + 1024 - k) * 2],
                            -Sg[((size_t)b * 513 + 1024 - k) * 2 + 1]);
  }
  __syncthreads();

#pragma unroll
  for (int sh = 9; sh >= 0; --sh) {
    const int h = 1 << sh;
#pragma unroll
    for (int bb = 0; bb < 2; ++bb) {
      const int bf = tid + bb * 256;
      const int pos = bf & (h - 1);
      const int i0 = ((bf >> sh) << (sh + 1)) + pos;
      const int i1 = i0 + h;
      const float2 u = x[XI(i0)], v = x[XI(i1)];
      const float2 w = tw[pos << (9 - sh)];
      const float2 d = make_float2(u.x - v.x, u.y - v.y);
      x[XI(i0)] = make_float2(u.x + v.x, u.y + v.y);
      x[XI(i1)] = make_float2(d.x * w.x - d.y * w.y, d.x * w.y + d.y * w.x);
    }
    __syncthreads();
  }

  for (int l = tid; l < 1024; l += 256)
    mv[b * 1024 + l] = x[XI(rev10(l))].x * (1.f / 1024.f);
}

// ===========================================================================
// prep: z in {0,1,2}: straight fp32->bf16 cvt of WQ/WK/WV; z==3: transposed
// cvt of Wfc.  z==0 also zeroes Sg (16*513*2 floats).
// ===========================================================================
__global__ __launch_bounds__(256) void prep(
    const float* __restrict__ WQ, const float* __restrict__ WK,
    const float* __restrict__ WV, const float* __restrict__ Wfc,
    short* __restrict__ wqb, short* __restrict__ wkb,
    short* __restrict__ wvb, short* __restrict__ wtf,
    float* __restrict__ Sg)
{
  const int z = blockIdx.z;
  const int tx = threadIdx.x & 31, ty = threadIdx.x >> 5;
  const int bx = blockIdx.x, by = blockIdx.y;
  if (z < 3) {
    const float* W = (z == 0) ? WQ : (z == 1) ? WK : WV;
    short* O = (z == 0) ? wqb : (z == 1) ? wkb : wvb;
#pragma unroll
    for (int s = 0; s < 32; s += 8) {
      const size_t o = (size_t)(by * 32 + ty + s) * 512 + bx * 32 + tx;
      O[o] = f2bf(W[o]);
    }
    if (z == 0) {
      const int gi = (by * 16 + bx) * 256 + (int)threadIdx.x;
      if (gi < 16 * 513 * 2) Sg[gi] = 0.f;
    }
  } else {
    __shared__ float t[32][33];
#pragma unroll
    for (int s = 0; s < 32; s += 8)
      t[ty + s][tx] = Wfc[(size_t)(by * 32 + ty + s) * 512 + bx * 32 + tx];
    __syncthreads();
#pragma unroll
    for (int s = 0; s < 32; s += 8)
      wtf[(size_t)(bx * 32 + ty + s) * 512 + by * 32 + tx] = f2bf(t[tx][ty + s]);
  }
}

__global__ __launch_bounds__(1024) void topk_softmax(
    const float* __restrict__ mean_value,
    int* __restrict__ idx_out, float* __restrict__ w_out)
{
  __shared__ float vals[1024];
  __shared__ int   inds[1024];
  __shared__ float bm[1024];
  __shared__ int   topi[TOPK];
  const int t = threadIdx.x;
  float s = 0.f;
  for (int b = 0; b < Bb; ++b) s += mean_value[b * Ll + t];
  bm[t] = s;
  __syncthreads();
  for (int k = 0; k < TOPK; ++k) {
    bool taken = false;
    for (int j = 0; j < k; ++j) taken |= (topi[j] == t);
    vals[t] = taken ? -INFINITY : bm[t];
    inds[t] = t;
    __syncthreads();
    for (int stride = 512; stride > 0; stride >>= 1) {
      if (t < stride) {
        if (vals[t + stride] > vals[t]) { vals[t] = vals[t + stride]; inds[t] = inds[t + stride]; }
      }
      __syncthreads();
    }
    if (t == 0) topi[k] = inds[0];
    __syncthreads();
  }
  if (t < TOPK) idx_out[t] = topi[t];
  if (t < Bb) {
    float wv[TOPK], mx = -INFINITY;
#pragma unroll
    for (int k = 0; k < TOPK; ++k) {
      wv[k] = mean_value[t * Ll + topi[k]] * (1.f / 512.f);
      mx = fmaxf(mx, wv[k]);
    }
    float sum = 0.f;
#pragma unroll
    for (int k = 0; k < TOPK; ++k) { wv[k] = expf(wv[k] - mx); sum += wv[k]; }
#pragma unroll
    for (int k = 0; k < TOPK; ++k) w_out[t * TOPK + k] = wv[k] / sum;
  }
}

// out[b][l][c] = sum_k w[b][k] * bf2f(U[b][(l+idx_k)%L][c])   (fp32 out)
__global__ __launch_bounds__(256) void gather_out(
    const short* __restrict__ U, const float* __restrict__ w,
    const int* __restrict__ idx, float* __restrict__ out)
{
  const int b = blockIdx.y;
  __shared__ float ww[8];
  __shared__ int   ii[8];
  if (threadIdx.x < TOPK) { ww[threadIdx.x] = w[b * TOPK + threadIdx.x]; ii[threadIdx.x] = idx[threadIdx.x]; }
  __syncthreads();
  const int l = blockIdx.x * 4 + (threadIdx.x >> 6);
  const int c = (threadIdx.x & 63) * 8;
  const short* ub = U + (size_t)b * Ll * Dd;
  float a[8] = {};
#pragma unroll
  for (int k = 0; k < TOPK; ++k) {
    const short8 vv = *(const short8*)&ub[(size_t)((l + ii[k]) & (Ll - 1)) * Dd + c];
    const float wk = ww[k];
#pragma unroll
    for (int e = 0; e < 8; ++e) a[e] = fmaf(wk, bf2f(vv[e]), a[e]);
  }
  float* op = &out[((size_t)b * Ll + l) * Dd + c];
  *(float4*)op       = make_float4(a[0], a[1], a[2], a[3]);
  *(float4*)(op + 4) = make_float4(a[4], a[5], a[6], a[7]);
}

}  // namespace

extern "C" void kernel_launch(void* const* d_in, const int* in_sizes, int n_in,
                              void* d_out, int out_size, void* d_ws, size_t ws_size,
                              hipStream_t stream)
{
  const float* Q   = (const float*)d_in[0];
  const float* K   = (const float*)d_in[1];
  const float* V   = (const float*)d_in[2];
  const float* WQ  = (const float*)d_in[4];
  const float* WK  = (const float*)d_in[5];
  const float* WV  = (const float*)d_in[6];
  const float* Wfc = (const float*)d_in[7];
  float* out = (float*)d_out;

  char* ws = (char*)d_ws;
  const size_t SB = (size_t)Bb * Ll * Dd * sizeof(short);   // 16 MiB
  short* Tt   = (short*)(ws);                               // [16][512][1024] bf16
  short* U    = (short*)(ws + 1 * SB);                      // [16][1024][512] bf16
  short* kbT  = (short*)(ws + 2 * SB);                      // [16][512][1024] bf16
  short* wqb  = (short*)(ws + 3 * SB);
  short* wkb  = wqb + 512 * 512;
  short* wvb  = wkb + 512 * 512;
  short* wtf  = wvb + 512 * 512;
  short* Gt   = wtf + 512 * 512;
  short* Ht   = Gt  + 512 * 512;
  float* mv   = (float*)(Ht + 512 * 512);                   // [16][1024]
  float* w    = mv + Bb * Ll;
  int*   idx  = (int*)(w + 128);
  float* Sg   = (float*)(idx + 64);                         // [16][513][2]

  // weights -> bf16 (wqb/wkb/wvb straight, wtf = Wfc^T); zero Sg
  prep<<<dim3(16, 16, 4), 256, 0, stream>>>(WQ, WK, WV, Wfc, wqb, wkb, wvb, wtf, Sg);

  // blocks 0..31: Gt = WK@wqb^T, Ht = wtf@wvb^T; blocks 32..543: K -> kbT
  g64<0><<<544, 256, 0, stream>>>(wkb, wtf, wqb, wvb, Gt, Ht, K, kbT);

  // z=0: Tt = bf16(Q @ Gt^T) transposed [b][he][t]; z=1: U = bf16(V @ Ht^T)
  g64<1><<<dim3(512, 1, 2), 256, 0, stream>>>(Q, V, Gt, Ht, Tt, U, nullptr, nullptr);

  // spectrum accumulation: Sg[b][k] = sum_he Qf * conj(Kf)  (radix-4)
  fftcorr<<<1024, 256, 0, stream>>>(Tt, kbT, Sg);

  // mv[b][l] = irfft(Sg[b])[l]
  ifft_mv<<<16, 256, 0, stream>>>(Sg, mv);

  topk_softmax<<<1, 1024, 0, stream>>>(mv, idx, w);

  gather_out<<<dim3(Ll / 4, Bb), 256, 0, stream>>>(U, w, idx, out);
}

// Round 19
// 132.820 us; speedup vs baseline: 1.0341x; 1.0341x over previous
//
#include <hip/hip_runtime.h>
#include <math.h>

namespace {

constexpr int Bb = 16;
constexpr int Ll = 1024;
constexpr int Dd = 512;
constexpr int TOPK = 6;
constexpr int Kc = 512;

typedef short  short4v __attribute__((ext_vector_type(4)));
typedef short  short8 __attribute__((ext_vector_type(8)));
typedef float  f32x4  __attribute__((ext_vector_type(4)));

__device__ __forceinline__ short f2bf(float x) {
  unsigned u = __builtin_bit_cast(unsigned, x);
  u += 0x7fffu + ((u >> 16) & 1u);          // RNE
  return (short)(u >> 16);
}
__device__ __forceinline__ float bf2f(short b) {
  unsigned u = ((unsigned)(unsigned short)b) << 16;
  return __builtin_bit_cast(float, u);
}
__device__ __forceinline__ void g2l16(const void* g, void* l) {
  __builtin_amdgcn_global_load_lds(
      (const __attribute__((address_space(1))) unsigned*)g,
      (__attribute__((address_space(3))) unsigned*)l, 16, 0, 0);
}
__device__ __forceinline__ short8 cvt8(float4 a, float4 b) {
  short8 o;
  o[0] = f2bf(a.x); o[1] = f2bf(a.y); o[2] = f2bf(a.z); o[3] = f2bf(a.w);
  o[4] = f2bf(b.x); o[5] = f2bf(b.y); o[6] = f2bf(b.z); o[7] = f2bf(b.w);
  return o;
}
__device__ __forceinline__ int rev10(int k) {
  return (int)(__builtin_bitreverse32((unsigned)k) >> 22);
}
__device__ __forceinline__ float2 cmul(float2 z, float2 w) {
  return make_float2(z.x * w.x - z.y * w.y, z.x * w.y + z.y * w.x);
}

#define BARRIER() do { asm volatile("" ::: "memory"); \
    __builtin_amdgcn_s_barrier(); \
    asm volatile("" ::: "memory"); } while (0)
#define VMCNT8() asm volatile("s_waitcnt vmcnt(8)" ::: "memory")
#define VMCNT4() asm volatile("s_waitcnt vmcnt(4)" ::: "memory")
#define VMCNT0() asm volatile("s_waitcnt vmcnt(0)" ::: "memory")
#define LGKM0()  do { asm volatile("s_waitcnt lgkmcnt(0)" ::: "memory"); \
    __builtin_amdgcn_sched_barrier(0); } while (0)

// ===========================================================================
// r10's g64 (refcheck'd): NT GEMM, 128x128 tile, BK=64 (8 K-steps), 256 thr
// (4 waves, 2m x 2n of 64x64), depth-2 LDS ring, counted entry-vmcnt,
// XOR-swizzled LDS.
// MODE 0: tiny — blocks 0..31: Gt/Ht GEMM (A,B bf16 -> C bf16).
//         blocks 32..543: K fp32 [b][t][he] -> kbT bf16 [b][he][t]
//         (32x32 LDS tile transpose, 16 tiles/block).
// MODE 1: front — A fp32 (split-stage + cvt), B bf16.
//         z==0: T = Q@Gt^T stored TRANSPOSED as Tt[b][he][t] (bf16).
//         z==1: U = V@Ht^T stored row-major [b][t][he] (bf16).
// ===========================================================================
template<int MODE>
__global__ __launch_bounds__(256) void g64(
    const void* __restrict__ A0, const void* __restrict__ A1,
    const short* __restrict__ B0, const short* __restrict__ B1,
    void* __restrict__ C0, void* __restrict__ C1,
    const float* __restrict__ KfIn, short* __restrict__ kbOut)
{
  __shared__ short lds[2][16384];   // per buf: A [0,8192), B [8192,16384)

  const int tid = threadIdx.x;
  int z, m0, n0;
  if (MODE == 0) {
    if (blockIdx.x >= 32) {                    // K -> kbT transpose slice
      float (*tf)[33] = (float(*)[33])lds;
      const int ci = blockIdx.x - 32;          // 0..511
      const int r8 = tid >> 5, cc = tid & 31;
      const int her = tid >> 3, c4 = (tid & 7) * 4;
#pragma unroll 1
      for (int it = 0; it < 16; ++it) {
        const int tile = ci * 16 + it;         // 8192 tiles: b(16) x ti(32) x hh(16)
        const int b  = tile >> 9;
        const int ti = (tile >> 4) & 31;
        const int hh = tile & 15;
        const float* src = KfIn + ((size_t)b * 1024 + ti * 32) * 512 + hh * 32;
#pragma unroll
        for (int rr = 0; rr < 4; ++rr)
          tf[r8 + rr * 8][cc] = src[(size_t)(r8 + rr * 8) * 512 + cc];
        __syncthreads();
        short4v o;
#pragma unroll
        for (int e = 0; e < 4; ++e) o[e] = f2bf(tf[c4 + e][her]);
        *(short4v*)&kbOut[((size_t)b * 512 + hh * 32 + her) * 1024 + ti * 32 + c4] = o;
        __syncthreads();
      }
      return;
    }
    z = blockIdx.x >> 4;
    const int s = blockIdx.x & 15;
    m0 = (s >> 2) * 128;  n0 = (s & 3) * 128;
  } else {
    z = blockIdx.z;
    const int fb = blockIdx.x;                 // 512, XCD chunk = 64
    const int s  = (fb & 7) * 64 + (fb >> 3);
    m0 = (s >> 2) * 128;  n0 = (s & 3) * 128;
  }

  const int rS  = tid >> 3;                    // 0..31
  const int c8S = (tid & 7) ^ (rS & 7);        // swizzled source 16B-slot
  const short* Ga = nullptr;  const float* Fa = nullptr;
  const short* Gb = nullptr;
  if (MODE == 0) {
    Ga = (const short*)(z ? A1 : A0) + (size_t)(m0 + rS) * Kc + c8S * 8;
    Gb = (z ? B1 : B0) + (size_t)(n0 + rS) * Kc + c8S * 8;
  } else {
    Fa = (const float*)(z ? A1 : A0) + (size_t)(m0 + rS) * Kc + c8S * 8;
    Gb = (z ? B1 : B0) + (size_t)(n0 + rS) * Kc + c8S * 8;
  }

  const int lane = tid & 63;
  const int wid  = tid >> 6;
  const int wr = wid >> 1, wn = wid & 1;
  const int lo = lane & 15, hi = lane >> 4;
  int aoff[2][4], boff[2][4];
#pragma unroll
  for (int i = 0; i < 4; ++i) {
    const int ar = wr * 64 + i * 16 + lo;
    const int br = wn * 64 + i * 16 + lo;
#pragma unroll
    for (int ks = 0; ks < 2; ++ks) {
      aoff[ks][i] = (ar * 8 + ((ks * 4 + hi) ^ (ar & 7))) * 8;
      boff[ks][i] = 8192 + (br * 8 + ((ks * 4 + hi) ^ (br & 7))) * 8;
    }
  }

  f32x4 acc[4][4];
#pragma unroll
  for (int i = 0; i < 4; ++i)
#pragma unroll
    for (int j = 0; j < 4; ++j) acc[i][j] = (f32x4){0.f, 0.f, 0.f, 0.f};

#define SG_A(buf, kt) do { _Pragma("unroll") \
    for (int i_ = 0; i_ < 4; ++i_) \
      g2l16(Ga + (size_t)i_ * 32 * Kc + (kt) * 64, &lds[buf][(i_ * 256 + tid) * 8]); } while (0)
#define SG_B(buf, kt) do { _Pragma("unroll") \
    for (int i_ = 0; i_ < 4; ++i_) \
      g2l16(Gb + (size_t)i_ * 32 * Kc + (kt) * 64, &lds[buf][8192 + (i_ * 256 + tid) * 8]); } while (0)
#define LD_F(eV, F, kt) do { _Pragma("unroll") \
    for (int i_ = 0; i_ < 4; ++i_) { \
      eV[2 * i_]     = *(const float4*)((F) + (size_t)i_ * 32 * Kc + (kt) * 64); \
      eV[2 * i_ + 1] = *(const float4*)((F) + (size_t)i_ * 32 * Kc + (kt) * 64 + 4); } } while (0)
#define WR_F(buf, opb, eV) do { _Pragma("unroll") \
    for (int i_ = 0; i_ < 4; ++i_) \
      *(short8*)&lds[buf][(opb) + (i_ * 256 + tid) * 8] = cvt8(eV[2 * i_], eV[2 * i_ + 1]); } while (0)

  {
    float4 e[8];
    if (MODE == 1) {
      SG_B(0, 0); LD_F(e, Fa, 0); WR_F(0, 0, e);
      SG_B(1, 1); LD_F(e, Fa, 1); WR_F(1, 0, e);
    } else {
      SG_A(0, 0); SG_B(0, 0);
      SG_A(1, 1); SG_B(1, 1);
    }
  }

  int cur = 0;
#pragma unroll 1
  for (int t = 0; t < 8; ++t) {
    if (t == 7)            VMCNT0();
    else if (MODE == 0)    VMCNT8();
    else                   VMCNT4();
    LGKM0();
    BARRIER();

    const short* L = lds[cur];
    const bool pf = (t < 6);
    float4 e[8];

    short8 af[4], bq[4];
#pragma unroll
    for (int i = 0; i < 4; ++i) af[i] = *(const short8*)(L + aoff[0][i]);
#pragma unroll
    for (int j = 0; j < 4; ++j) bq[j] = *(const short8*)(L + boff[0][j]);
    if (pf && MODE == 1) LD_F(e, Fa, t + 2);
#pragma unroll
    for (int i = 0; i < 4; ++i)
#pragma unroll
      for (int j = 0; j < 4; ++j)
        acc[i][j] = __builtin_amdgcn_mfma_f32_16x16x32_bf16(af[i], bq[j], acc[i][j], 0, 0, 0);
#pragma unroll
    for (int i = 0; i < 4; ++i) af[i] = *(const short8*)(L + aoff[1][i]);
#pragma unroll
    for (int j = 0; j < 4; ++j) bq[j] = *(const short8*)(L + boff[1][j]);
#pragma unroll
    for (int i = 0; i < 4; ++i)
#pragma unroll
      for (int j = 0; j < 4; ++j)
        acc[i][j] = __builtin_amdgcn_mfma_f32_16x16x32_bf16(af[i], bq[j], acc[i][j], 0, 0, 0);

    BARRIER();

    if (pf) {
      if (MODE == 1)      { SG_B(cur, t + 2); WR_F(cur, 0, e); }
      else                { SG_A(cur, t + 2); SG_B(cur, t + 2); }
    }
    cur ^= 1;
  }
#undef SG_A
#undef SG_B
#undef LD_F
#undef WR_F

  if (MODE == 1 && z == 0) {
    // transposed store: Tt[b][he][t], 4 consecutive t per short4
    short* Tt = (short*)C0;
#pragma unroll
    for (int i = 0; i < 4; ++i) {
      const int rowb = m0 + wr * 64 + i * 16 + hi * 4;       // global t-row, 4-aligned
      const size_t bbase = (size_t)(rowb >> 10) * 512;       // batch * 512 he
#pragma unroll
      for (int j = 0; j < 4; ++j) {
        const int col = n0 + wn * 64 + j * 16 + lo;          // he
        short4v o;
#pragma unroll
        for (int r = 0; r < 4; ++r) o[r] = f2bf(acc[i][j][r]);
        *(short4v*)&Tt[(bbase + col) * 1024 + (rowb & 1023)] = o;
      }
    }
  } else {
    short* C = (short*)(z ? C1 : C0);
#pragma unroll
    for (int i = 0; i < 4; ++i)
#pragma unroll
      for (int r = 0; r < 4; ++r) {
        const size_t row = m0 + wr * 64 + i * 16 + hi * 4 + r;
#pragma unroll
        for (int j = 0; j < 4; ++j)
          C[row * Dd + n0 + wn * 64 + j * 16 + lo] = f2bf(acc[i][j][r]);
      }
  }
}

// ===========================================================================
// fftcorr v4: DUAL-FFT radix-4 blocks.  512 thr process TWO independent
// 1024-pt FFTs concurrently (slot f = tid>>8, butterfly idx ft = tid&255);
// per-slot sac[2][513] (no cross-slot race), merged at the end.
// Per block: 8 he as 4 dual-iterations -> barrier count halves vs r18 and
// each barrier covers 2x work.  1024 blocks x 8 waves = 4 blocks/CU.
// Radix-4 math byte-identical to r18 (validated): bitrev2 slot trick,
// XI skew, same extraction.
// ===========================================================================
#define XI(i) ((i) + ((i) >> 4))
__global__ __launch_bounds__(512) void fftcorr(
    const short* __restrict__ Tt, const short* __restrict__ kbT,
    float* __restrict__ Sg)
{
  __shared__ float2 x[2][1088];                // 1024 + 64 pad per slot
  __shared__ float2 tw[1024];
  __shared__ float2 sac[2][513];

  const int tid = threadIdx.x;                 // 0..511
  const int f   = tid >> 8;                    // FFT slot
  const int ft  = tid & 255;                   // butterfly index
  const int b   = blockIdx.x >> 6;
  const int he0 = (blockIdx.x & 63) * 8;

  for (int j = tid; j < 1024; j += 512) {
    float sv, cv;
    sincosf(6.283185307179586f * (float)j / 1024.f, &sv, &cv);
    tw[j] = make_float2(cv, -sv);              // W = exp(-2*pi*i*j/1024)
  }
  for (int k = tid; k < 513; k += 512) {
    sac[0][k] = make_float2(0.f, 0.f);
    sac[1][k] = make_float2(0.f, 0.f);
  }
  __syncthreads();

#pragma unroll 1
  for (int it = 0; it < 4; ++it) {
    const int he = he0 + it * 2 + f;
    const short* q = Tt  + ((size_t)b * 512 + he) * 1024;
    const short* p = kbT + ((size_t)b * 512 + he) * 1024;
    {
      const int t4 = ft * 4;
      const short4v qv = *(const short4v*)&q[t4];
      const short4v pv = *(const short4v*)&p[t4];
#pragma unroll
      for (int e = 0; e < 4; ++e)
        x[f][XI(t4 + e)] = make_float2(bf2f(qv[e]), bf2f(pv[e]));
    }
    __syncthreads();

    // 5 radix-4 DIF stages: h = 256, 64, 16, 4, 1
#pragma unroll
    for (int s = 0; s < 5; ++s) {
      const int l2h = 8 - 2 * s;
      const int h   = 1 << l2h;
      const int pos = ft & (h - 1);
      const int i0  = ((ft >> l2h) << (l2h + 2)) + pos;
      const float2 a = x[f][XI(i0)];
      const float2 bv = x[f][XI(i0 + h)];
      const float2 c = x[f][XI(i0 + 2 * h)];
      const float2 d = x[f][XI(i0 + 3 * h)];
      const float2 apc = make_float2(a.x + c.x, a.y + c.y);
      const float2 amc = make_float2(a.x - c.x, a.y - c.y);
      const float2 bpd = make_float2(bv.x + d.x, bv.y + d.y);
      const float2 bmd = make_float2(bv.x - d.x, bv.y - d.y);
      const float2 y0 = make_float2(apc.x + bpd.x, apc.y + bpd.y);
      const float2 y2 = make_float2(apc.x - bpd.x, apc.y - bpd.y);
      const float2 y1 = make_float2(amc.x + bmd.y, amc.y - bmd.x);   // amc - i*bmd
      const float2 y3 = make_float2(amc.x - bmd.y, amc.y + bmd.x);   // amc + i*bmd
      const int e1 = pos << (2 * s);
      x[f][XI(i0)]         = y0;
      x[f][XI(i0 + h)]     = cmul(y2, tw[2 * e1]);   // slot1 <- j=2
      x[f][XI(i0 + 2 * h)] = cmul(y1, tw[e1]);       // slot2 <- j=1
      x[f][XI(i0 + 3 * h)] = cmul(y3, tw[3 * e1]);
      __syncthreads();
    }

    // extraction: A = (Z[k]+conj(Z[N-k]))/2, B = (Z[k]-conj(Z[N-k]))/(2i),
    // S += A*conj(B)   (per-slot accumulator)
#pragma unroll
    for (int kk = 0; kk < 3; ++kk) {
      const int k = (kk < 2) ? (ft + kk * 256) : 512;
      if (kk < 2 || ft == 0) {
        const float2 Zk = x[f][XI(rev10(k))];
        const float2 Zm = x[f][XI(rev10((1024 - k) & 1023))];
        const float2 A = make_float2(0.5f * (Zk.x + Zm.x), 0.5f * (Zk.y - Zm.y));
        const float2 B = make_float2(0.5f * (Zk.y + Zm.y), -0.5f * (Zk.x - Zm.x));
        sac[f][k].x += A.x * B.x + A.y * B.y;
        sac[f][k].y += A.y * B.x - A.x * B.y;
      }
    }
    __syncthreads();
  }

  for (int k = tid; k < 513; k += 512) {
    atomicAdd(&Sg[((size_t)b * 513 + k) * 2 + 0], sac[0][k].x + sac[1][k].x);
    atomicAdd(&Sg[((size_t)b * 513 + k) * 2 + 1], sac[0][k].y + sac[1][k].y);
  }
}

// ===========================================================================
// ifft_mv: mv[b][l] = irfft(Sg[b])[l].  Hermitian extension to 1024, one
// conj-twiddle radix-2 DIF FFT, output (bit-reversed) real part / 1024.
// ===========================================================================
__global__ __launch_bounds__(256) void ifft_mv(
    const float* __restrict__ Sg, float* __restrict__ mv)
{
  __shared__ float2 x[1088];
  __shared__ float2 tw[512];
  const int tid = threadIdx.x;
  const int b = blockIdx.x;

  for (int j = tid; j < 512; j += 256) {
    float sv, cv;
    sincosf(6.283185307179586f * (float)j / 1024.f, &sv, &cv);
    tw[j] = make_float2(cv, sv);               // conjugate twiddles
  }
  for (int k = tid; k < 1024; k += 256) {
    if (k <= 512)
      x[XI(k)] = make_float2(Sg[((size_t)b * 513 + k) * 2], Sg[((size_t)b * 513 + k) * 2 + 1]);
    else
      x[XI(k)] = make_float2(Sg[((size_t)b * 513 + 1024 - k) * 2],
                            -Sg[((size_t)b * 513 + 1024 - k) * 2 + 1]);
  }
  __syncthreads();

#pragma unroll
  for (int sh = 9; sh >= 0; --sh) {
    const int h = 1 << sh;
#pragma unroll
    for (int bb = 0; bb < 2; ++bb) {
      const int bf = tid + bb * 256;
      const int pos = bf & (h - 1);
      const int i0 = ((bf >> sh) << (sh + 1)) + pos;
      const int i1 = i0 + h;
      const float2 u = x[XI(i0)], v = x[XI(i1)];
      const float2 w = tw[pos << (9 - sh)];
      const float2 d = make_float2(u.x - v.x, u.y - v.y);
      x[XI(i0)] = make_float2(u.x + v.x, u.y + v.y);
      x[XI(i1)] = make_float2(d.x * w.x - d.y * w.y, d.x * w.y + d.y * w.x);
    }
    __syncthreads();
  }

  for (int l = tid; l < 1024; l += 256)
    mv[b * 1024 + l] = x[XI(rev10(l))].x * (1.f / 1024.f);
}

// ===========================================================================
// prep: z in {0,1,2}: straight fp32->bf16 cvt of WQ/WK/WV; z==3: transposed
// cvt of Wfc.  z==0 also zeroes Sg (16*513*2 floats).
// ===========================================================================
__global__ __launch_bounds__(256) void prep(
    const float* __restrict__ WQ, const float* __restrict__ WK,
    const float* __restrict__ WV, const float* __restrict__ Wfc,
    short* __restrict__ wqb, short* __restrict__ wkb,
    short* __restrict__ wvb, short* __restrict__ wtf,
    float* __restrict__ Sg)
{
  const int z = blockIdx.z;
  const int tx = threadIdx.x & 31, ty = threadIdx.x >> 5;
  const int bx = blockIdx.x, by = blockIdx.y;
  if (z < 3) {
    const float* W = (z == 0) ? WQ : (z == 1) ? WK : WV;
    short* O = (z == 0) ? wqb : (z == 1) ? wkb : wvb;
#pragma unroll
    for (int s = 0; s < 32; s += 8) {
      const size_t o = (size_t)(by * 32 + ty + s) * 512 + bx * 32 + tx;
      O[o] = f2bf(W[o]);
    }
    if (z == 0) {
      const int gi = (by * 16 + bx) * 256 + (int)threadIdx.x;
      if (gi < 16 * 513 * 2) Sg[gi] = 0.f;
    }
  } else {
    __shared__ float t[32][33];
#pragma unroll
    for (int s = 0; s < 32; s += 8)
      t[ty + s][tx] = Wfc[(size_t)(by * 32 + ty + s) * 512 + bx * 32 + tx];
    __syncthreads();
#pragma unroll
    for (int s = 0; s < 32; s += 8)
      wtf[(size_t)(bx * 32 + ty + s) * 512 + by * 32 + tx] = f2bf(t[tx][ty + s]);
  }
}

__global__ __launch_bounds__(1024) void topk_softmax(
    const float* __restrict__ mean_value,
    int* __restrict__ idx_out, float* __restrict__ w_out)
{
  __shared__ float vals[1024];
  __shared__ int   inds[1024];
  __shared__ float bm[1024];
  __shared__ int   topi[TOPK];
  const int t = threadIdx.x;
  float s = 0.f;
  for (int b = 0; b < Bb; ++b) s += mean_value[b * Ll + t];
  bm[t] = s;
  __syncthreads();
  for (int k = 0; k < TOPK; ++k) {
    bool taken = false;
    for (int j = 0; j < k; ++j) taken |= (topi[j] == t);
    vals[t] = taken ? -INFINITY : bm[t];
    inds[t] = t;
    __syncthreads();
    for (int stride = 512; stride > 0; stride >>= 1) {
      if (t < stride) {
        if (vals[t + stride] > vals[t]) { vals[t] = vals[t + stride]; inds[t] = inds[t + stride]; }
      }
      __syncthreads();
    }
    if (t == 0) topi[k] = inds[0];
    __syncthreads();
  }
  if (t < TOPK) idx_out[t] = topi[t];
  if (t < Bb) {
    float wv[TOPK], mx = -INFINITY;
#pragma unroll
    for (int k = 0; k < TOPK; ++k) {
      wv[k] = mean_value[t * Ll + topi[k]] * (1.f / 512.f);
      mx = fmaxf(mx, wv[k]);
    }
    float sum = 0.f;
#pragma unroll
    for (int k = 0; k < TOPK; ++k) { wv[k] = expf(wv[k] - mx); sum += wv[k]; }
#pragma unroll
    for (int k = 0; k < TOPK; ++k) w_out[t * TOPK + k] = wv[k] / sum;
  }
}

// out[b][l][c] = sum_k w[b][k] * bf2f(U[b][(l+idx_k)%L][c])   (fp32 out)
__global__ __launch_bounds__(256) void gather_out(
    const short* __restrict__ U, const float* __restrict__ w,
    const int* __restrict__ idx, float* __restrict__ out)
{
  const int b = blockIdx.y;
  __shared__ float ww[8];
  __shared__ int   ii[8];
  if (threadIdx.x < TOPK) { ww[threadIdx.x] = w[b * TOPK + threadIdx.x]; ii[threadIdx.x] = idx[threadIdx.x]; }
  __syncthreads();
  const int l = blockIdx.x * 4 + (threadIdx.x >> 6);
  const int c = (threadIdx.x & 63) * 8;
  const short* ub = U + (size_t)b * Ll * Dd;
  float a[8] = {};
#pragma unroll
  for (int k = 0; k < TOPK; ++k) {
    const short8 vv = *(const short8*)&ub[(size_t)((l + ii[k]) & (Ll - 1)) * Dd + c];
    const float wk = ww[k];
#pragma unroll
    for (int e = 0; e < 8; ++e) a[e] = fmaf(wk, bf2f(vv[e]), a[e]);
  }
  float* op = &out[((size_t)b * Ll + l) * Dd + c];
  *(float4*)op       = make_float4(a[0], a[1], a[2], a[3]);
  *(float4*)(op + 4) = make_float4(a[4], a[5], a[6], a[7]);
}

}  // namespace

extern "C" void kernel_launch(void* const* d_in, const int* in_sizes, int n_in,
                              void* d_out, int out_size, void* d_ws, size_t ws_size,
                              hipStream_t stream)
{
  const float* Q   = (const float*)d_in[0];
  const float* K   = (const float*)d_in[1];
  const float* V   = (const float*)d_in[2];
  const float* WQ  = (const float*)d_in[4];
  const float* WK  = (const float*)d_in[5];
  const float* WV  = (const float*)d_in[6];
  const float* Wfc = (const float*)d_in[7];
  float* out = (float*)d_out;

  char* ws = (char*)d_ws;
  const size_t SB = (size_t)Bb * Ll * Dd * sizeof(short);   // 16 MiB
  short* Tt   = (short*)(ws);                               // [16][512][1024] bf16
  short* U    = (short*)(ws + 1 * SB);                      // [16][1024][512] bf16
  short* kbT  = (short*)(ws + 2 * SB);                      // [16][512][1024] bf16
  short* wqb  = (short*)(ws + 3 * SB);
  short* wkb  = wqb + 512 * 512;
  short* wvb  = wkb + 512 * 512;
  short* wtf  = wvb + 512 * 512;
  short* Gt   = wtf + 512 * 512;
  short* Ht   = Gt  + 512 * 512;
  float* mv   = (float*)(Ht + 512 * 512);                   // [16][1024]
  float* w    = mv + Bb * Ll;
  int*   idx  = (int*)(w + 128);
  float* Sg   = (float*)(idx + 64);                         // [16][513][2]

  // weights -> bf16 (wqb/wkb/wvb straight, wtf = Wfc^T); zero Sg
  prep<<<dim3(16, 16, 4), 256, 0, stream>>>(WQ, WK, WV, Wfc, wqb, wkb, wvb, wtf, Sg);

  // blocks 0..31: Gt = WK@wqb^T, Ht = wtf@wvb^T; blocks 32..543: K -> kbT
  g64<0><<<544, 256, 0, stream>>>(wkb, wtf, wqb, wvb, Gt, Ht, K, kbT);

  // z=0: Tt = bf16(Q @ Gt^T) transposed [b][he][t]; z=1: U = bf16(V @ Ht^T)
  g64<1><<<dim3(512, 1, 2), 256, 0, stream>>>(Q, V, Gt, Ht, Tt, U, nullptr, nullptr);

  // spectrum accumulation: Sg[b][k] = sum_he Qf * conj(Kf)  (dual radix-4)
  fftcorr<<<1024, 512, 0, stream>>>(Tt, kbT, Sg);

  // mv[b][l] = irfft(Sg[b])[l]
  ifft_mv<<<16, 256, 0, stream>>>(Sg, mv);

  topk_softmax<<<1, 1024, 0, stream>>>(mv, idx, w);

  gather_out<<<dim3(Ll / 4, Bb), 256, 0, stream>>>(U, w, idx, out);
}